// Round 1
// baseline (873.332 us; speedup 1.0000x reference)
//
#include <hip/hip_runtime.h>
#include <math.h>

// ---------------------------------------------------------------------------
// StageA GNN: encoder -> L x (gate-proj, edge scatter, node update+LN) -> head
// Key algebraic opt: concat(h_s,h_d)@gate_w1 == h_s@W_top + h_d@W_bot,
// precomputed per-node (16x FLOP reduction since E/N = 16).
// ---------------------------------------------------------------------------

__device__ __forceinline__ float wave_sum64(float v) {
    #pragma unroll
    for (int o = 32; o > 0; o >>= 1) v += __shfl_xor(v, o, 64);
    return v;
}

__global__ __launch_bounds__(256) void rho_kernel(
    const float* __restrict__ rr, float* __restrict__ rho, int N) {
    int i = blockIdx.x * blockDim.x + threadIdx.x;
    if (i < N) rho[i] = 1.0f / (1.0f + __expf(-rr[i]));
}

// h = relu(relu(x@W1+b1)@W2+b2); wave-per-row, W1 in LDS (64KB), W2 via L1.
__global__ __launch_bounds__(256) void enc_kernel(
    const float* __restrict__ x, const float* __restrict__ w1,
    const float* __restrict__ b1, const float* __restrict__ w2,
    const float* __restrict__ b2, float* __restrict__ h, int N, int C) {
    __shared__ float ws1[256 * 64];  // 64 KB
    for (int i = threadIdx.x; i < C * 64; i += blockDim.x) ws1[i] = w1[i];
    __syncthreads();
    const int lane = threadIdx.x & 63;
    const int wid  = blockIdx.x * (blockDim.x >> 6) + (threadIdx.x >> 6);
    const int nw   = gridDim.x * (blockDim.x >> 6);
    const float b1l = b1[lane], b2l = b2[lane];
    for (int r = wid; r < N; r += nw) {
        const float4* xr = (const float4*)(x + (size_t)r * C);
        float acc = 0.f;
        for (int k4 = 0; k4 < C / 4; ++k4) {
            float4 xv = xr[k4];
            int k = k4 * 4;
            acc = fmaf(ws1[(k + 0) * 64 + lane], xv.x, acc);
            acc = fmaf(ws1[(k + 1) * 64 + lane], xv.y, acc);
            acc = fmaf(ws1[(k + 2) * 64 + lane], xv.z, acc);
            acc = fmaf(ws1[(k + 3) * 64 + lane], xv.w, acc);
        }
        float t1 = fmaxf(acc + b1l, 0.f);
        float acc2 = 0.f;
        #pragma unroll
        for (int k = 0; k < 64; ++k) {
            float tv = __shfl(t1, k, 64);
            acc2 = fmaf(w2[k * 64 + lane], tv, acc2);
        }
        h[(size_t)r * 64 + lane] = fmaxf(acc2 + b2l, 0.f);
    }
}

// a = h@gw1[0:64] + gb1 ; bb = h@gw1[64:128]   (bias folded into a)
__global__ __launch_bounds__(256) void gateproj_kernel(
    const float* __restrict__ h, const float* __restrict__ gw1,
    const float* __restrict__ gb1, float* __restrict__ a,
    float* __restrict__ bb, int N) {
    __shared__ float ws[128 * 64];  // 32 KB
    for (int i = threadIdx.x; i < 128 * 64; i += blockDim.x) ws[i] = gw1[i];
    __syncthreads();
    const int lane = threadIdx.x & 63;
    const int wid  = blockIdx.x * (blockDim.x >> 6) + (threadIdx.x >> 6);
    const int nw   = gridDim.x * (blockDim.x >> 6);
    const float gb = gb1[lane];
    for (int r = wid; r < N; r += nw) {
        float hv = h[(size_t)r * 64 + lane];
        float aacc = 0.f, bacc = 0.f;
        #pragma unroll
        for (int k = 0; k < 64; ++k) {
            float tv = __shfl(hv, k, 64);
            aacc = fmaf(ws[k * 64 + lane], tv, aacc);
            bacc = fmaf(ws[(64 + k) * 64 + lane], tv, bacc);
        }
        a[(size_t)r * 64 + lane]  = aacc + gb;
        bb[(size_t)r * 64 + lane] = bacc;
    }
}

// Per-edge: z=relu(a[s]+bb[d]); gate=sigmoid(z.gw2+gb2); w=base*gate*rho_s*rho_d
// scatter m[d] += w*h[s]; deg[d] += w.   Wave per edge, lane = feature.
__global__ __launch_bounds__(256) void edge_kernel(
    const int* __restrict__ src, const int* __restrict__ dst,
    const float* __restrict__ base_w, const float* __restrict__ rho,
    const float* __restrict__ a, const float* __restrict__ bb,
    const float* __restrict__ h, const float* __restrict__ gw2,
    const float* __restrict__ gb2, float* __restrict__ m,
    float* __restrict__ deg, int E) {
    const int lane = threadIdx.x & 63;
    const int wid  = blockIdx.x * (blockDim.x >> 6) + (threadIdx.x >> 6);
    const int nw   = gridDim.x * (blockDim.x >> 6);
    const float gv = gw2[lane];
    const float gb = gb2[0];
    for (int e = wid; e < E; e += nw) {
        int s = src[e], d = dst[e];
        float av = a[(size_t)s * 64 + lane];
        float bv = bb[(size_t)d * 64 + lane];
        float z  = fmaxf(av + bv, 0.f);
        float t  = wave_sum64(z * gv);
        float gate = 1.0f / (1.0f + __expf(-(t + gb)));
        float w = base_w[e] * gate * rho[s] * rho[d];
        float hv = h[(size_t)s * 64 + lane];
        atomicAdd(&m[(size_t)d * 64 + lane], w * hv);
        if (lane == 0) atomicAdd(&deg[d], w);
    }
}

// neigh=m/(deg+eps); u=relu(neigh@W1+b1)@W2+b2; h=LN(h+u)*g+b  (in place)
__global__ __launch_bounds__(256) void update_kernel(
    const float* __restrict__ m, const float* __restrict__ deg,
    const float* __restrict__ w1, const float* __restrict__ b1,
    const float* __restrict__ w2, const float* __restrict__ b2,
    const float* __restrict__ lng, const float* __restrict__ lnb,
    float* __restrict__ h, int N) {
    __shared__ float ws1[64 * 64], ws2[64 * 64];  // 16 KB + 16 KB
    for (int i = threadIdx.x; i < 4096; i += blockDim.x) {
        ws1[i] = w1[i];
        ws2[i] = w2[i];
    }
    __syncthreads();
    const int lane = threadIdx.x & 63;
    const int wid  = blockIdx.x * (blockDim.x >> 6) + (threadIdx.x >> 6);
    const int nw   = gridDim.x * (blockDim.x >> 6);
    const float b1l = b1[lane], b2l = b2[lane];
    const float gl = lng[lane], bl = lnb[lane];
    for (int r = wid; r < N; r += nw) {
        float dg = deg[r];
        float neigh = m[(size_t)r * 64 + lane] / (dg + 1e-8f);
        float acc = 0.f;
        #pragma unroll
        for (int k = 0; k < 64; ++k) {
            float tv = __shfl(neigh, k, 64);
            acc = fmaf(ws1[k * 64 + lane], tv, acc);
        }
        float t = fmaxf(acc + b1l, 0.f);
        float acc2 = 0.f;
        #pragma unroll
        for (int k = 0; k < 64; ++k) {
            float tv = __shfl(t, k, 64);
            acc2 = fmaf(ws2[k * 64 + lane], tv, acc2);
        }
        float pre = h[(size_t)r * 64 + lane] + acc2 + b2l;
        float s1 = wave_sum64(pre);
        float s2 = wave_sum64(pre * pre);
        float mean = s1 * (1.0f / 64.0f);
        float var  = s2 * (1.0f / 64.0f) - mean * mean;
        float hn = (pre - mean) * rsqrtf(var + 1e-5f) * gl + bl;
        h[(size_t)r * 64 + lane] = hn;
    }
}

// U = softplus(h @ toU_w + toU_b), K=32
__global__ __launch_bounds__(256) void out_kernel(
    const float* __restrict__ h, const float* __restrict__ tw,
    const float* __restrict__ tb, float* __restrict__ U, int N) {
    int gid = blockIdx.x * blockDim.x + threadIdx.x;
    int n = gid >> 5;
    int k = gid & 31;
    if (n >= N) return;
    float acc = tb[k];
    const float* hr = h + (size_t)n * 64;
    #pragma unroll 8
    for (int j = 0; j < 64; ++j) acc = fmaf(hr[j], tw[j * 32 + k], acc);
    float sp = acc > 0.f ? acc + log1pf(__expf(-acc)) : log1pf(__expf(acc));
    U[(size_t)n * 32 + k] = sp;
}

extern "C" void kernel_launch(void* const* d_in, const int* in_sizes, int n_in,
                              void* d_out, int out_size, void* d_ws, size_t ws_size,
                              hipStream_t stream) {
    const float* x       = (const float*)d_in[0];
    const int*   src     = (const int*)d_in[1];
    const int*   dst     = (const int*)d_in[2];
    const float* base_w  = (const float*)d_in[3];
    const float* enc_w1  = (const float*)d_in[4];
    const float* enc_b1  = (const float*)d_in[5];
    const float* enc_w2  = (const float*)d_in[6];
    const float* enc_b2  = (const float*)d_in[7];
    const float* gate_w1 = (const float*)d_in[8];
    const float* gate_b1 = (const float*)d_in[9];
    const float* gate_w2 = (const float*)d_in[10];
    const float* gate_b2 = (const float*)d_in[11];
    const float* upd_w1  = (const float*)d_in[12];
    const float* upd_b1  = (const float*)d_in[13];
    const float* upd_w2  = (const float*)d_in[14];
    const float* upd_b2  = (const float*)d_in[15];
    const float* ln_g    = (const float*)d_in[16];
    const float* ln_b    = (const float*)d_in[17];
    const float* rho_raw = (const float*)d_in[18];
    const float* toU_w   = (const float*)d_in[19];
    const float* toU_b   = (const float*)d_in[20];

    const int N = in_sizes[18];          // 50000
    const int C = in_sizes[0] / N;       // 256
    const int E = in_sizes[1];           // 800000
    const int L = 2;

    float* ws  = (float*)d_ws;
    float* rho = ws;                          // N
    float* h   = rho + N;                     // N*64
    float* a   = h  + (size_t)N * 64;         // N*64
    float* bb  = a  + (size_t)N * 64;         // N*64
    float* m   = bb + (size_t)N * 64;         // N*64
    float* deg = m  + (size_t)N * 64;         // N   (contiguous with m for 1 memset)

    rho_kernel<<<(N + 255) / 256, 256, 0, stream>>>(rho_raw, rho, N);
    enc_kernel<<<512, 256, 0, stream>>>(x, enc_w1, enc_b1, enc_w2, enc_b2, h, N, C);

    for (int l = 0; l < L; ++l) {
        gateproj_kernel<<<1024, 256, 0, stream>>>(h, gate_w1, gate_b1, a, bb, N);
        hipMemsetAsync(m, 0, ((size_t)N * 64 + N) * sizeof(float), stream);
        edge_kernel<<<2048, 256, 0, stream>>>(src, dst, base_w, rho, a, bb, h,
                                              gate_w2, gate_b2, m, deg, E);
        update_kernel<<<1024, 256, 0, stream>>>(
            m, deg, upd_w1 + (size_t)l * 4096, upd_b1 + l * 64,
            upd_w2 + (size_t)l * 4096, upd_b2 + l * 64,
            ln_g + l * 64, ln_b + l * 64, h, N);
    }

    out_kernel<<<((N * 32) + 255) / 256, 256, 0, stream>>>(h, toU_w, toU_b,
                                                           (float*)d_out, N);
}